// Round 1
// baseline (1387.342 us; speedup 1.0000x reference)
//
#include <hip/hip_runtime.h>
#include <stdint.h>

#define D_DIM 1024
#define B_ROWS 65536

typedef __bf16 bf16x8 __attribute__((ext_vector_type(8)));
typedef float f32x4 __attribute__((ext_vector_type(4)));

typedef __attribute__((address_space(1))) uint8_t ga_u8;
typedef __attribute__((address_space(3))) uint8_t lds_u8;

// async global->LDS DMA, 16 bytes per lane. LDS dest must be
// wave-uniform-base + lane*16 contiguous (it is, by construction below).
__device__ __forceinline__ void dma16(const void* g, void* l) {
  __builtin_amdgcn_global_load_lds((ga_u8*)(uintptr_t)g,
                                   (lds_u8*)(uint32_t)(uintptr_t)l, 16, 0, 0);
}

__device__ __forceinline__ uint16_t bf16_rne(float x) {
  union { float f; uint32_t u; } v; v.f = x;
  uint32_t u = v.u + 0x7FFFu + ((v.u >> 16) & 1u);
  return (uint16_t)(u >> 16);
}
__device__ __forceinline__ float bf16_f32(uint16_t h) {
  union { uint32_t u; float f; } v; v.u = (uint32_t)h << 16;
  return v.f;
}
__device__ __forceinline__ void split2(float x, uint16_t& h, uint16_t& l) {
  h = bf16_rne(x);
  l = bf16_rne(x - bf16_f32(h));
}

// HW packed fp32->bf16 convert: D[15:0]=bf16(lo), D[31:16]=bf16(hi).
// One instruction per 2 elements (vs ~5 for the integer-RNE path).
__device__ __forceinline__ uint32_t cvtpk(float lo, float hi) {
  uint32_t r;
  asm("v_cvt_pk_bf16_f32 %0, %1, %2" : "=v"(r) : "v"(lo), "v"(hi));
  return r;
}

// ---------------------------------------------------------------------------
// Weight fold via split-bf16 MFMA (fp32-equivalent accuracy, 3 MFMAs):
// M[n][k] = sum_j WO[n][j] * WV[j][k], WV = w_in rows [2D,3D). Output bf16.
// Tile 128x128, 4 waves 2x2, wave 64x64 (4x4 of 16x16x32). BJ=32.
// B operand (WV^T) is transposed into LDS during staging.
// ---------------------------------------------------------------------------
__global__ __launch_bounds__(256) void fold_w(
    const float* __restrict__ w_in_ab, const float* __restrict__ w_out_ab,
    const float* __restrict__ w_in_ba, const float* __restrict__ w_out_ba,
    uint16_t* __restrict__ M_ab, uint16_t* __restrict__ M_ba)
{
  const int z = blockIdx.z;
  const float* WO = z ? w_out_ba : w_out_ab;
  const float* WV = (z ? w_in_ba : w_in_ab) + 2 * D_DIM * D_DIM;
  uint16_t* M = z ? M_ba : M_ab;
  const int n0 = blockIdx.y * 128, k0 = blockIdx.x * 128;

  __shared__ __align__(16) uint16_t Ah[128 * 32], Al[128 * 32];
  __shared__ __align__(16) uint16_t Bh[128 * 32], Bl[128 * 32];

  const int t = threadIdx.x, lane = t & 63, w = t >> 6;
  const int wm = w >> 1, wn = w & 1;
  const int lr = lane & 15, lq = lane >> 4;

  f32x4 acc[4][4] = {};

  const int ar = t >> 1, ac = (t & 1) * 16;           // A: row ar, 16 j-cols
  const float* ag = WO + (uint64_t)(n0 + ar) * D_DIM + ac;
  const int bj = t >> 3, bc = (t & 7) * 16;           // B: j-row bj, 16 k-cols
  const float* bgp = WV + (uint64_t)bj * D_DIM + k0 + bc;

  for (int j0 = 0; j0 < D_DIM; j0 += 32) {
    __syncthreads();
    {  // stage WO tile (rows n, cols j) split into Ah/Al, row-major [128][32]
      float av[16];
      const float4* s = (const float4*)(ag + j0);
#pragma unroll
      for (int q = 0; q < 4; ++q) {
        float4 f = s[q];
        av[4*q] = f.x; av[4*q+1] = f.y; av[4*q+2] = f.z; av[4*q+3] = f.w;
      }
      uint16_t hh[16], ll[16];
#pragma unroll
      for (int i = 0; i < 16; ++i) split2(av[i], hh[i], ll[i]);
      uint4* dh = (uint4*)(Ah + t * 16);
      uint4* dl = (uint4*)(Al + t * 16);
#pragma unroll
      for (int q = 0; q < 2; ++q) {
        uint4 vh, vl;
        vh.x = (uint32_t)hh[8*q+0] | ((uint32_t)hh[8*q+1] << 16);
        vh.y = (uint32_t)hh[8*q+2] | ((uint32_t)hh[8*q+3] << 16);
        vh.z = (uint32_t)hh[8*q+4] | ((uint32_t)hh[8*q+5] << 16);
        vh.w = (uint32_t)hh[8*q+6] | ((uint32_t)hh[8*q+7] << 16);
        vl.x = (uint32_t)ll[8*q+0] | ((uint32_t)ll[8*q+1] << 16);
        vl.y = (uint32_t)ll[8*q+2] | ((uint32_t)ll[8*q+3] << 16);
        vl.z = (uint32_t)ll[8*q+4] | ((uint32_t)ll[8*q+5] << 16);
        vl.w = (uint32_t)ll[8*q+6] | ((uint32_t)ll[8*q+7] << 16);
        dh[q] = vh; dl[q] = vl;
      }
    }
    {  // stage WV tile transposed: Bh/Bl layout [k][j] (k rows of 32 j)
      const float* s = bgp + (uint64_t)j0 * D_DIM;
#pragma unroll
      for (int i = 0; i < 16; ++i) {
        float x = s[i];
        uint16_t h, l; split2(x, h, l);
        Bh[(bc + i) * 32 + bj] = h;
        Bl[(bc + i) * 32 + bj] = l;
      }
    }
    __syncthreads();

    bf16x8 ah[4], al[4], bh[4], bl[4];
    const uint4* avh = (const uint4*)Ah; const uint4* avl = (const uint4*)Al;
    const uint4* bvh = (const uint4*)Bh; const uint4* bvl = (const uint4*)Bl;
#pragma unroll
    for (int mt = 0; mt < 4; ++mt) {
      int r = (wm * 64 + mt * 16 + lr) * 4 + lq;
      ah[mt] = __builtin_bit_cast(bf16x8, avh[r]);
      al[mt] = __builtin_bit_cast(bf16x8, avl[r]);
    }
#pragma unroll
    for (int nt = 0; nt < 4; ++nt) {
      int r = (wn * 64 + nt * 16 + lr) * 4 + lq;
      bh[nt] = __builtin_bit_cast(bf16x8, bvh[r]);
      bl[nt] = __builtin_bit_cast(bf16x8, bvl[r]);
    }
#pragma unroll
    for (int mt = 0; mt < 4; ++mt)
#pragma unroll
      for (int nt = 0; nt < 4; ++nt) {
        acc[mt][nt] = __builtin_amdgcn_mfma_f32_16x16x32_bf16(ah[mt], bh[nt], acc[mt][nt], 0, 0, 0);
        acc[mt][nt] = __builtin_amdgcn_mfma_f32_16x16x32_bf16(ah[mt], bl[nt], acc[mt][nt], 0, 0, 0);
        acc[mt][nt] = __builtin_amdgcn_mfma_f32_16x16x32_bf16(al[mt], bh[nt], acc[mt][nt], 0, 0, 0);
      }
  }

#pragma unroll
  for (int nt = 0; nt < 4; ++nt) {
    const int col = k0 + wn * 64 + nt * 16 + lr;
#pragma unroll
    for (int mt = 0; mt < 4; ++mt) {
      const int rowb = n0 + wm * 64 + mt * 16 + lq * 4;
#pragma unroll
      for (int r = 0; r < 4; ++r)
        M[(uint64_t)(rowb + r) * D_DIM + col] = bf16_rne(acc[mt][nt][r]);
    }
  }
}

// ---------------------------------------------------------------------------
// Folded bias: bias[n] = b_out[n] + sum_j WO[n][j] * b_in[2D + j]
// ---------------------------------------------------------------------------
__global__ __launch_bounds__(256) void fold_bias(
    const float* __restrict__ w_out_ab, const float* __restrict__ b_in_ab,
    const float* __restrict__ b_out_ab,
    const float* __restrict__ w_out_ba, const float* __restrict__ b_in_ba,
    const float* __restrict__ b_out_ba,
    float* __restrict__ bias_ab, float* __restrict__ bias_ba)
{
  const int z = blockIdx.y;
  const float* WO  = z ? w_out_ba : w_out_ab;
  const float* bin = (z ? b_in_ba : b_in_ab) + 2 * D_DIM;
  const float* bo  = z ? b_out_ba : b_out_ab;
  float* bias = z ? bias_ba : bias_ab;

  const int n = blockIdx.x, t = threadIdx.x;
  float p = 0.f;
  for (int j = t; j < D_DIM; j += 256)
    p += WO[(uint64_t)n * D_DIM + j] * bin[j];
  for (int off = 32; off; off >>= 1) p += __shfl_down(p, off, 64);
  __shared__ float ws[4];
  if ((t & 63) == 0) ws[t >> 6] = p;
  __syncthreads();
  if (t == 0) bias[n] = ws[0] + ws[1] + ws[2] + ws[3] + bo[n];
}

// ---------------------------------------------------------------------------
// Main GEMM, conversion fused: out[:, z*D : z*D+D] = bf16(A_z) @ M_z^T + bias_z
// A_z is fp32 in HBM; converted in-register via v_cvt_pk_bf16_f32 during
// LDS staging (no separate conv pass, no bf16 copy of A in the workspace).
// BM=256, BN=128, BK=32. 4 waves (2x2), wave tile 128x64 (8x4 of 16x16x32).
// XCD swizzle: 1D grid, lin -> (xcd=lin&7, ntile=(lin>>3)&7, group=lin>>6);
// panel mp = group*8+xcd. The 8 n-tiles of one A-panel occupy 8 consecutive
// slots on ONE XCD -> A panel fetched from HBM once, 7 L2 hits.
// A staging map: 4 lanes per row (32 fp32 cols = 4 x 32B), so each wave's
// issue covers 16 rows x 128B contiguous -> coalesced at cache-line grain.
// ---------------------------------------------------------------------------
__global__ __launch_bounds__(256, 2) void gemm_fused(
    const float* __restrict__ A0, const float* __restrict__ A1,
    const uint16_t* __restrict__ M_ab, const uint16_t* __restrict__ M_ba,
    const float* __restrict__ bias_ab, const float* __restrict__ bias_ba,
    float* __restrict__ out)
{
  const uint32_t lin = blockIdx.x;
  const uint32_t xcd = lin & 7, j = (lin >> 3) & 7, g = lin >> 6;
  const uint32_t mp = g * 8 + xcd;          // 0..511
  const uint32_t z  = mp >> 8;
  const uint32_t m0 = (mp & 255) * 256;
  const uint32_t n0 = j * 128;

  const float* A = z ? A1 : A0;
  const uint16_t* W = z ? M_ba : M_ab;
  const float* bias = z ? bias_ba : bias_ab;

  __shared__ __align__(16) uint16_t As[256 * 32];  // 16 KB
  __shared__ __align__(16) uint16_t Bs[128 * 32];  //  8 KB

  const int t = threadIdx.x, lane = t & 63, w = t >> 6;
  const int wm = w >> 1, wn = w & 1;
  const int lr = lane & 15, lq = lane >> 4;

  f32x4 acc[8][4] = {};

  // A staging: issue q in 0..3 -> row q*64 + (t>>2), cols (t&3)*8 .. +8 fp32
  const int arow = t >> 2, acol = (t & 3) * 8;
  const float* ag = A + (uint64_t)(m0 + arow) * D_DIM + acol;
  uint16_t* al = As + arow * 32 + acol;

  // B staging via global_load_lds (M is bf16, 2 MB -> L2 resident)
  const int qrow = lane >> 2;           // 0..15
  const int qcol = (lane & 3) * 8;      // element col base
  const uint16_t* bg = W + (uint64_t)(n0 + w * 32 + qrow) * D_DIM + qcol;
  uint16_t* bl0 = Bs + w * 1024 + lane * 8;   // + q*512 per issue

  for (int k0 = 0; k0 < D_DIM; k0 += 32) {
    __syncthreads();
    // issue B DMA first; it proceeds asynchronously under A convert
#pragma unroll
    for (int q = 0; q < 2; ++q)
      dma16(bg + k0 + q * 16 * D_DIM, bl0 + q * 512);
    // A: load fp32, cvt_pk -> bf16, write LDS (one b128 per issue)
#pragma unroll
    for (int q = 0; q < 4; ++q) {
      const float4* s = (const float4*)(ag + (uint64_t)q * 64 * D_DIM + k0);
      float4 f0 = s[0], f1 = s[1];
      uint4 pv;
      pv.x = cvtpk(f0.x, f0.y); pv.y = cvtpk(f0.z, f0.w);
      pv.z = cvtpk(f1.x, f1.y); pv.w = cvtpk(f1.z, f1.w);
      *(uint4*)(al + q * 64 * 32) = pv;
    }
    __syncthreads();

    bf16x8 a[8], b[4];
    const uint4* asv = (const uint4*)As;
    const uint4* bsv = (const uint4*)Bs;
#pragma unroll
    for (int mt = 0; mt < 8; ++mt)
      a[mt] = __builtin_bit_cast(bf16x8, asv[(wm * 128 + mt * 16 + lr) * 4 + lq]);
#pragma unroll
    for (int nt = 0; nt < 4; ++nt)
      b[nt] = __builtin_bit_cast(bf16x8, bsv[(wn * 64 + nt * 16 + lr) * 4 + lq]);
#pragma unroll
    for (int mt = 0; mt < 8; ++mt)
#pragma unroll
      for (int nt = 0; nt < 4; ++nt)
        acc[mt][nt] = __builtin_amdgcn_mfma_f32_16x16x32_bf16(a[mt], b[nt], acc[mt][nt], 0, 0, 0);
  }

  // Epilogue: C/D layout col=lane&15, row=(lane>>4)*4+reg.
  // out is write-once/never-read: nontemporal so the 512 MB of stores don't
  // evict the fp32 A panels the XCD swizzle keeps L2-resident.
  const uint32_t col_off = z * D_DIM;
#pragma unroll
  for (int nt = 0; nt < 4; ++nt) {
    const int col = n0 + wn * 64 + nt * 16 + lr;
    const float bv = bias[col];
#pragma unroll
    for (int mt = 0; mt < 8; ++mt) {
      const int row = m0 + wm * 128 + mt * 16 + lq * 4;
      float* op = out + (uint64_t)row * (2 * D_DIM) + col_off + col;
#pragma unroll
      for (int r = 0; r < 4; ++r)
        __builtin_nontemporal_store(acc[mt][nt][r] + bv,
                                    op + (uint64_t)r * (2 * D_DIM));
    }
  }
}

extern "C" void kernel_launch(void* const* d_in, const int* in_sizes, int n_in,
                              void* d_out, int out_size, void* d_ws, size_t ws_size,
                              hipStream_t stream) {
  const float* feat_a   = (const float*)d_in[0];
  const float* feat_b   = (const float*)d_in[1];
  const float* w_in_ab  = (const float*)d_in[2];
  const float* b_in_ab  = (const float*)d_in[3];
  const float* w_out_ab = (const float*)d_in[4];
  const float* b_out_ab = (const float*)d_in[5];
  const float* w_in_ba  = (const float*)d_in[6];
  const float* b_in_ba  = (const float*)d_in[7];
  const float* w_out_ba = (const float*)d_in[8];
  const float* b_out_ba = (const float*)d_in[9];
  float* out = (float*)d_out;

  uint8_t* ws = (uint8_t*)d_ws;
  uint16_t* M_ab = (uint16_t*)ws;
  uint16_t* M_ba = (uint16_t*)(ws + (2u << 20));
  float* bias_ab = (float*)(ws + (4u << 20));
  float* bias_ba = (float*)(ws + (4u << 20) + 4096);

  fold_w<<<dim3(8, 8, 2), 256, 0, stream>>>(
      w_in_ab, w_out_ab, w_in_ba, w_out_ba, M_ab, M_ba);
  fold_bias<<<dim3(1024, 2), 256, 0, stream>>>(
      w_out_ab, b_in_ab, b_out_ab, w_out_ba, b_in_ba, b_out_ba,
      bias_ab, bias_ba);

  // z=0: out[:, :D]  = bf16(feat_b) @ M_ab^T + bias_ab
  // z=1: out[:, D:]  = bf16(feat_a) @ M_ba^T + bias_ba
  gemm_fused<<<4096, 256, 0, stream>>>(
      feat_b, feat_a, M_ab, M_ba, bias_ab, bias_ba, out);
}